// Round 2
// baseline (295.912 us; speedup 1.0000x reference)
//
#include <hip/hip_runtime.h>
#include <hip/hip_bf16.h>
#include <stdint.h>

#define NROWS 8192
#define DIMQ 1024
#define DIMU 1024
#define NCH 16

#define BM 128
#define BN 128
#define BK 32
#define LDSTR 40   // bf16 elems per LDS row (32 + 8 pad -> 80B stride, 2-way bank alias = free)

typedef __attribute__((ext_vector_type(4))) float f32x4;
typedef __attribute__((ext_vector_type(4))) short s16x4;
typedef __attribute__((ext_vector_type(8))) short bf16x8;

__device__ __forceinline__ short f2bf(float f) {
    union { __hip_bfloat16 h; short s; } u;
    u.h = __float2bfloat16(f);
    return u.s;
}

// ---------------- gate: top-2 select + normalize + bucket by chart ----------------
__global__ void gate_kernel(const float* __restrict__ weights,
                            int* __restrict__ cnt,
                            int* __restrict__ rowlist,
                            float* __restrict__ wgt) {
    int b = blockIdx.x * blockDim.x + threadIdx.x;
    if (b >= NROWS) return;
    float w[NCH];
    const f32x4* wp = reinterpret_cast<const f32x4*>(weights + (size_t)b * NCH);
#pragma unroll
    for (int i = 0; i < 4; ++i) {
        f32x4 v = wp[i];
        w[i * 4 + 0] = v[0]; w[i * 4 + 1] = v[1];
        w[i * 4 + 2] = v[2]; w[i * 4 + 3] = v[3];
    }
    // argmax (lowest index wins ties, matching jax.lax.top_k stability)
    int i0 = 0; float v0 = w[0];
#pragma unroll
    for (int i = 1; i < NCH; ++i) if (w[i] > v0) { v0 = w[i]; i0 = i; }
    int i1 = (i0 == 0) ? 1 : 0; float v1 = w[i1];
#pragma unroll
    for (int i = 0; i < NCH; ++i) if (i != i0 && w[i] > v1) { v1 = w[i]; i1 = i; }

    float s = v0 + v1;
    s = (s < 1e-8f) ? 1e-8f : s;
    float n0 = v0 / s, n1 = v1 / s;

    int p0 = atomicAdd(&cnt[i0], 1);
    rowlist[(size_t)i0 * NROWS + p0] = b;
    wgt[(size_t)i0 * NROWS + p0] = n0;
    int p1 = atomicAdd(&cnt[i1], 1);
    rowlist[(size_t)i1 * NROWS + p1] = b;
    wgt[(size_t)i1 * NROWS + p1] = n1;
}

// ---------------- grouped gather-GEMM: out[row] += w * (q[row] @ W[c]^T) ----------------
// grid: (DIMU/BN, NROWS/BM worst-case row tiles, NCH). Early-exit on bucket count.
__global__ __launch_bounds__(256, 2) void moe_gemm(
    const float* __restrict__ q, const float* __restrict__ Wst,
    const int* __restrict__ cnt, const int* __restrict__ rowlist,
    const float* __restrict__ wgt, float* __restrict__ out)
{
    const int c  = blockIdx.z;
    const int n0 = blockIdx.x * BN;
    const int m0 = blockIdx.y * BM;
    const int count = cnt[c];
    if (m0 >= count) return;

    __shared__ short sA[BM * LDSTR];
    __shared__ short sB[BN * LDSTR];
    __shared__ int   sRow[BM];
    __shared__ float sW[BM];

    const int t = threadIdx.x;
    if (t < BM) {
        int gi = m0 + t;
        int r = 0; float w = 0.f;
        if (gi < count) {
            r = rowlist[(size_t)c * NROWS + gi];
            w = wgt[(size_t)c * NROWS + gi];
        }
        sRow[t] = r; sW[t] = w;
    }
    __syncthreads();

    // staging map: 4 float4 per thread per matrix. f = t + i*256 -> row=f>>3, col4=f&7
    const float* aBase[4];
    const float* bBase[4];
    int ldsOff[4];
#pragma unroll
    for (int i = 0; i < 4; ++i) {
        int f  = t + i * 256;
        int r  = f >> 3;
        int c4 = f & 7;
        aBase[i]  = q   + (size_t)sRow[r] * DIMQ + c4 * 4;
        bBase[i]  = Wst + (size_t)c * (DIMU * (size_t)DIMQ) + (size_t)(n0 + r) * DIMQ + c4 * 4;
        ldsOff[i] = r * LDSTR + c4 * 4;
    }

    const int lane = t & 63;
    const int wv   = t >> 6;
    const int wm   = (wv >> 1) * 64;   // wave row offset in tile
    const int wn   = (wv & 1) * 64;    // wave col offset in tile
    const int rr   = lane & 15;
    const int g    = lane >> 4;

    f32x4 acc[4][4];
#pragma unroll
    for (int r = 0; r < 4; ++r)
#pragma unroll
        for (int cc = 0; cc < 4; ++cc)
            acc[r][cc] = (f32x4){0.f, 0.f, 0.f, 0.f};

    // prefetch K-step 0 into registers
    f32x4 pa[4], pb[4];
#pragma unroll
    for (int i = 0; i < 4; ++i) {
        pa[i] = *reinterpret_cast<const f32x4*>(aBase[i]);
        pb[i] = *reinterpret_cast<const f32x4*>(bBase[i]);
    }

    const int NKT = DIMQ / BK;
    for (int kt = 0; kt < NKT; ++kt) {
        __syncthreads();   // previous tile's compute done before LDS overwrite
#pragma unroll
        for (int i = 0; i < 4; ++i) {
            s16x4 va, vb;
#pragma unroll
            for (int j = 0; j < 4; ++j) { va[j] = f2bf(pa[i][j]); vb[j] = f2bf(pb[i][j]); }
            *reinterpret_cast<s16x4*>(&sA[ldsOff[i]]) = va;
            *reinterpret_cast<s16x4*>(&sB[ldsOff[i]]) = vb;
        }
        __syncthreads();

        if (kt + 1 < NKT) {
            int k = (kt + 1) * BK;
#pragma unroll
            for (int i = 0; i < 4; ++i) {
                pa[i] = *reinterpret_cast<const f32x4*>(aBase[i] + k);
                pb[i] = *reinterpret_cast<const f32x4*>(bBase[i] + k);
            }
        }

        bf16x8 af[4], bfr[4];
#pragma unroll
        for (int r = 0; r < 4; ++r) {
            af[r]  = *reinterpret_cast<const bf16x8*>(&sA[(wm + r * 16 + rr) * LDSTR + g * 8]);
            bfr[r] = *reinterpret_cast<const bf16x8*>(&sB[(wn + r * 16 + rr) * LDSTR + g * 8]);
        }
#pragma unroll
        for (int r = 0; r < 4; ++r)
#pragma unroll
            for (int cc = 0; cc < 4; ++cc)
                acc[r][cc] = __builtin_amdgcn_mfma_f32_16x16x32_bf16(af[r], bfr[cc], acc[r][cc], 0, 0, 0);
    }

    // epilogue: scale by gate weight, scatter-add into out (each out row hit by exactly 2 charts)
#pragma unroll
    for (int r = 0; r < 4; ++r) {
#pragma unroll
        for (int cc = 0; cc < 4; ++cc) {
#pragma unroll
            for (int j = 0; j < 4; ++j) {
                int rowInTile = wm + r * 16 + g * 4 + j;   // C/D: row=(lane>>4)*4+reg, col=lane&15 (m89)
                int gi = m0 + rowInTile;
                if (gi < count) {
                    int   orow = sRow[rowInTile];
                    float w    = sW[rowInTile];
                    int   col  = n0 + wn + cc * 16 + rr;
                    atomicAdd(&out[(size_t)orow * DIMU + col], acc[r][cc][j] * w);
                }
            }
        }
    }
}

extern "C" void kernel_launch(void* const* d_in, const int* in_sizes, int n_in,
                              void* d_out, int out_size, void* d_ws, size_t ws_size,
                              hipStream_t stream) {
    const float* q  = (const float*)d_in[0];
    const float* w  = (const float*)d_in[1];
    const float* Ws = (const float*)d_in[2];
    float* out = (float*)d_out;

    // ws layout: [0,256) counters, then rowlist int[16][8192], then wgt float[16][8192]  (~1.05 MB)
    int*   cnt     = (int*)d_ws;
    int*   rowlist = (int*)((char*)d_ws + 256);
    float* wgt     = (float*)((char*)d_ws + 256 + (size_t)NCH * NROWS * sizeof(int));

    hipMemsetAsync(d_ws, 0, 256, stream);
    hipMemsetAsync(d_out, 0, (size_t)out_size * sizeof(float), stream);

    gate_kernel<<<NROWS / 256, 256, 0, stream>>>(w, cnt, rowlist, wgt);

    dim3 grid(DIMU / BN, NROWS / BM, NCH);
    moe_gemm<<<grid, 256, 0, stream>>>(q, Ws, cnt, rowlist, wgt, out);
}

// Round 3
// 228.466 us; speedup vs baseline: 1.2952x; 1.2952x over previous
//
#include <hip/hip_runtime.h>
#include <hip/hip_bf16.h>
#include <stdint.h>

#define NROWS 8192
#define DIMQ 1024
#define DIMU 1024
#define NCH 16

#define BM 128
#define BN 128

typedef __attribute__((ext_vector_type(4))) float f32x4;
typedef __attribute__((ext_vector_type(4))) short s16x4;
typedef __attribute__((ext_vector_type(8))) short bf16x8;

__device__ __forceinline__ short f2bf(float f) {
    union { __hip_bfloat16 h; short s; } u;
    u.h = __float2bfloat16(f);
    return u.s;
}

// ---------------- f32 -> bf16 bulk convert (8 elems/thread/iter) ----------------
__global__ void cvt_kernel(const float* __restrict__ src, short* __restrict__ dst, int n8) {
    int i = blockIdx.x * blockDim.x + threadIdx.x;
    int stride = gridDim.x * blockDim.x;
    for (; i < n8; i += stride) {
        const f32x4* p = reinterpret_cast<const f32x4*>(src + (size_t)i * 8);
        f32x4 a = p[0], b = p[1];
        bf16x8 o;
        o[0] = f2bf(a[0]); o[1] = f2bf(a[1]); o[2] = f2bf(a[2]); o[3] = f2bf(a[3]);
        o[4] = f2bf(b[0]); o[5] = f2bf(b[1]); o[6] = f2bf(b[2]); o[7] = f2bf(b[3]);
        *reinterpret_cast<bf16x8*>(dst + (size_t)i * 8) = o;
    }
}

// ---------------- gate: top-2 + normalize, LDS histogram to cut atomic contention ----------------
__global__ void gate_kernel(const float* __restrict__ weights,
                            int* __restrict__ cnt,
                            int* __restrict__ rowlist,
                            float* __restrict__ wgt) {
    __shared__ int lcnt[NCH];
    __shared__ int lbase[NCH];
    const int t = threadIdx.x;
    const int b = blockIdx.x * blockDim.x + t;
    if (t < NCH) lcnt[t] = 0;
    __syncthreads();

    float w[NCH];
    const f32x4* wp = reinterpret_cast<const f32x4*>(weights + (size_t)b * NCH);
#pragma unroll
    for (int i = 0; i < 4; ++i) {
        f32x4 v = wp[i];
        w[i * 4 + 0] = v[0]; w[i * 4 + 1] = v[1];
        w[i * 4 + 2] = v[2]; w[i * 4 + 3] = v[3];
    }
    int i0 = 0; float v0 = w[0];
#pragma unroll
    for (int i = 1; i < NCH; ++i) if (w[i] > v0) { v0 = w[i]; i0 = i; }
    int i1 = (i0 == 0) ? 1 : 0; float v1 = w[i1];
#pragma unroll
    for (int i = 0; i < NCH; ++i) if (i != i0 && w[i] > v1) { v1 = w[i]; i1 = i; }
    float s = v0 + v1;
    s = (s < 1e-8f) ? 1e-8f : s;
    float n0 = v0 / s, n1 = v1 / s;

    int p0 = atomicAdd(&lcnt[i0], 1);
    int p1 = atomicAdd(&lcnt[i1], 1);
    __syncthreads();
    if (t < NCH) lbase[t] = atomicAdd(&cnt[t], lcnt[t]);
    __syncthreads();

    int o0 = lbase[i0] + p0;
    int o1 = lbase[i1] + p1;
    rowlist[(size_t)i0 * NROWS + o0] = b;  wgt[(size_t)i0 * NROWS + o0] = n0;
    rowlist[(size_t)i1 * NROWS + o1] = b;  wgt[(size_t)i1 * NROWS + o1] = n1;
}

// ================= bf16 grouped gather-GEMM =================
// BK=64, LDS stride 72 shorts (144B): b128 read+write both spread uniformly
// over the 8 bank-groups (minimal cycles). 16 K-iters (was 32) halves barriers.
#define BKB 64
#define LDSTRB 72

__global__ __launch_bounds__(256, 3) void moe_gemm_bf(
    const short* __restrict__ qb, const short* __restrict__ Wb,
    const int* __restrict__ cnt, const int* __restrict__ rowlist,
    const float* __restrict__ wgt, float* __restrict__ out)
{
    const int c  = blockIdx.z;
    const int n0 = blockIdx.x * BN;
    const int m0 = blockIdx.y * BM;
    const int count = cnt[c];
    if (m0 >= count) return;

    __shared__ short sA[BM * LDSTRB];
    __shared__ short sB[BN * LDSTRB];
    __shared__ int   sRow[BM];
    __shared__ float sW[BM];

    const int t = threadIdx.x;
    if (t < BM) {
        int gi = m0 + t;
        int r = 0; float wv_ = 0.f;
        if (gi < count) {
            r   = rowlist[(size_t)c * NROWS + gi];
            wv_ = wgt[(size_t)c * NROWS + gi];
        }
        sRow[t] = r; sW[t] = wv_;
    }
    __syncthreads();

    // staging: tile is 128 rows x 64 bf16 = 1024 chunks of 16B; 4 chunks/thread/matrix
    const short* aSrc[4];
    const short* bSrc[4];
    int ldsO[4];
#pragma unroll
    for (int i = 0; i < 4; ++i) {
        int f  = t + i * 256;
        int r  = f >> 3;
        int c8 = f & 7;
        aSrc[i] = qb + (size_t)sRow[r] * DIMQ + c8 * 8;
        bSrc[i] = Wb + (size_t)c * ((size_t)DIMU * DIMQ) + (size_t)(n0 + r) * DIMQ + c8 * 8;
        ldsO[i] = r * LDSTRB + c8 * 8;
    }

    const int lane = t & 63;
    const int wv   = t >> 6;
    const int wm   = (wv >> 1) * 64;
    const int wn   = (wv & 1) * 64;
    const int rr   = lane & 15;
    const int g    = lane >> 4;

    f32x4 acc[4][4];
#pragma unroll
    for (int r = 0; r < 4; ++r)
#pragma unroll
        for (int cc = 0; cc < 4; ++cc)
            acc[r][cc] = (f32x4){0.f, 0.f, 0.f, 0.f};

    bf16x8 pa[4], pb[4];
#pragma unroll
    for (int i = 0; i < 4; ++i) {
        pa[i] = *reinterpret_cast<const bf16x8*>(aSrc[i]);
        pb[i] = *reinterpret_cast<const bf16x8*>(bSrc[i]);
    }

    const int NKT = DIMQ / BKB;  // 16
    for (int kt = 0; kt < NKT; ++kt) {
        __syncthreads();
#pragma unroll
        for (int i = 0; i < 4; ++i) {
            *reinterpret_cast<bf16x8*>(&sA[ldsO[i]]) = pa[i];
            *reinterpret_cast<bf16x8*>(&sB[ldsO[i]]) = pb[i];
        }
        __syncthreads();

        if (kt + 1 < NKT) {
            int k = (kt + 1) * BKB;
#pragma unroll
            for (int i = 0; i < 4; ++i) {
                pa[i] = *reinterpret_cast<const bf16x8*>(aSrc[i] + k);
                pb[i] = *reinterpret_cast<const bf16x8*>(bSrc[i] + k);
            }
        }

#pragma unroll
        for (int ks = 0; ks < 2; ++ks) {
            bf16x8 af[4], bfr[4];
#pragma unroll
            for (int r = 0; r < 4; ++r) {
                af[r]  = *reinterpret_cast<const bf16x8*>(&sA[(wm + r * 16 + rr) * LDSTRB + ks * 32 + g * 8]);
                bfr[r] = *reinterpret_cast<const bf16x8*>(&sB[(wn + r * 16 + rr) * LDSTRB + ks * 32 + g * 8]);
            }
#pragma unroll
            for (int r = 0; r < 4; ++r)
#pragma unroll
                for (int cc = 0; cc < 4; ++cc)
                    acc[r][cc] = __builtin_amdgcn_mfma_f32_16x16x32_bf16(af[r], bfr[cc], acc[r][cc], 0, 0, 0);
        }
    }

#pragma unroll
    for (int r = 0; r < 4; ++r) {
#pragma unroll
        for (int cc = 0; cc < 4; ++cc) {
#pragma unroll
            for (int j = 0; j < 4; ++j) {
                int rowInTile = wm + r * 16 + g * 4 + j;   // C/D: row=(lane>>4)*4+reg, col=lane&15 (m89)
                int gi = m0 + rowInTile;
                if (gi < count) {
                    int   orow = sRow[rowInTile];
                    float wgx  = sW[rowInTile];
                    int   col  = n0 + wn + cc * 16 + rr;
                    atomicAdd(&out[(size_t)orow * DIMU + col], acc[r][cc][j] * wgx);
                }
            }
        }
    }
}

// ================= fallback f32-staging GEMM (proven round-2 path) =================
#define BKF 32
#define LDSTRF 40

__global__ __launch_bounds__(256, 2) void moe_gemm_f32(
    const float* __restrict__ q, const float* __restrict__ Wst,
    const int* __restrict__ cnt, const int* __restrict__ rowlist,
    const float* __restrict__ wgt, float* __restrict__ out)
{
    const int c  = blockIdx.z;
    const int n0 = blockIdx.x * BN;
    const int m0 = blockIdx.y * BM;
    const int count = cnt[c];
    if (m0 >= count) return;

    __shared__ short sA[BM * LDSTRF];
    __shared__ short sB[BN * LDSTRF];
    __shared__ int   sRow[BM];
    __shared__ float sW[BM];

    const int t = threadIdx.x;
    if (t < BM) {
        int gi = m0 + t;
        int r = 0; float w = 0.f;
        if (gi < count) {
            r = rowlist[(size_t)c * NROWS + gi];
            w = wgt[(size_t)c * NROWS + gi];
        }
        sRow[t] = r; sW[t] = w;
    }
    __syncthreads();

    const float* aBase[4];
    const float* bBase[4];
    int ldsOff[4];
#pragma unroll
    for (int i = 0; i < 4; ++i) {
        int f  = t + i * 256;
        int r  = f >> 3;
        int c4 = f & 7;
        aBase[i]  = q   + (size_t)sRow[r] * DIMQ + c4 * 4;
        bBase[i]  = Wst + (size_t)c * ((size_t)DIMU * DIMQ) + (size_t)(n0 + r) * DIMQ + c4 * 4;
        ldsOff[i] = r * LDSTRF + c4 * 4;
    }

    const int lane = t & 63;
    const int wv   = t >> 6;
    const int wm   = (wv >> 1) * 64;
    const int wn   = (wv & 1) * 64;
    const int rr   = lane & 15;
    const int g    = lane >> 4;

    f32x4 acc[4][4];
#pragma unroll
    for (int r = 0; r < 4; ++r)
#pragma unroll
        for (int cc = 0; cc < 4; ++cc)
            acc[r][cc] = (f32x4){0.f, 0.f, 0.f, 0.f};

    f32x4 pa[4], pb[4];
#pragma unroll
    for (int i = 0; i < 4; ++i) {
        pa[i] = *reinterpret_cast<const f32x4*>(aBase[i]);
        pb[i] = *reinterpret_cast<const f32x4*>(bBase[i]);
    }

    const int NKT = DIMQ / BKF;
    for (int kt = 0; kt < NKT; ++kt) {
        __syncthreads();
#pragma unroll
        for (int i = 0; i < 4; ++i) {
            s16x4 va, vb;
#pragma unroll
            for (int j = 0; j < 4; ++j) { va[j] = f2bf(pa[i][j]); vb[j] = f2bf(pb[i][j]); }
            *reinterpret_cast<s16x4*>(&sA[ldsOff[i]]) = va;
            *reinterpret_cast<s16x4*>(&sB[ldsOff[i]]) = vb;
        }
        __syncthreads();

        if (kt + 1 < NKT) {
            int k = (kt + 1) * BKF;
#pragma unroll
            for (int i = 0; i < 4; ++i) {
                pa[i] = *reinterpret_cast<const f32x4*>(aBase[i] + k);
                pb[i] = *reinterpret_cast<const f32x4*>(bBase[i] + k);
            }
        }

        bf16x8 af[4], bfr[4];
#pragma unroll
        for (int r = 0; r < 4; ++r) {
            af[r]  = *reinterpret_cast<const bf16x8*>(&sA[(wm + r * 16 + rr) * LDSTRF + g * 8]);
            bfr[r] = *reinterpret_cast<const bf16x8*>(&sB[(wn + r * 16 + rr) * LDSTRF + g * 8]);
        }
#pragma unroll
        for (int r = 0; r < 4; ++r)
#pragma unroll
            for (int cc = 0; cc < 4; ++cc)
                acc[r][cc] = __builtin_amdgcn_mfma_f32_16x16x32_bf16(af[r], bfr[cc], acc[r][cc], 0, 0, 0);
    }

#pragma unroll
    for (int r = 0; r < 4; ++r) {
#pragma unroll
        for (int cc = 0; cc < 4; ++cc) {
#pragma unroll
            for (int j = 0; j < 4; ++j) {
                int rowInTile = wm + r * 16 + g * 4 + j;
                int gi = m0 + rowInTile;
                if (gi < count) {
                    int   orow = sRow[rowInTile];
                    float w    = sW[rowInTile];
                    int   col  = n0 + wn + cc * 16 + rr;
                    atomicAdd(&out[(size_t)orow * DIMU + col], acc[r][cc][j] * w);
                }
            }
        }
    }
}

extern "C" void kernel_launch(void* const* d_in, const int* in_sizes, int n_in,
                              void* d_out, int out_size, void* d_ws, size_t ws_size,
                              hipStream_t stream) {
    const float* q  = (const float*)d_in[0];
    const float* w  = (const float*)d_in[1];
    const float* Ws = (const float*)d_in[2];
    float* out = (float*)d_out;

    const size_t qbf_bytes  = (size_t)NROWS * DIMQ * 2;            // 16.78 MB
    const size_t wbf_bytes  = (size_t)NCH * DIMU * (size_t)DIMQ * 2; // 33.55 MB
    const size_t meta_bytes = 256 + (size_t)NCH * NROWS * (sizeof(int) + sizeof(float));
    char* ws = (char*)d_ws;

    if (ws_size >= qbf_bytes + wbf_bytes + meta_bytes) {
        short* qb      = (short*)ws;
        short* Wb      = (short*)(ws + qbf_bytes);
        int*   cnt     = (int*)(ws + qbf_bytes + wbf_bytes);
        int*   rowlist = (int*)(ws + qbf_bytes + wbf_bytes + 256);
        float* wgt     = (float*)(ws + qbf_bytes + wbf_bytes + 256 + (size_t)NCH * NROWS * sizeof(int));

        hipMemsetAsync(cnt, 0, 256, stream);
        hipMemsetAsync(d_out, 0, (size_t)out_size * sizeof(float), stream);

        cvt_kernel<<<2048, 256, 0, stream>>>(q,  qb, NROWS * DIMQ / 8);
        cvt_kernel<<<2048, 256, 0, stream>>>(Ws, Wb, NCH * DIMU * DIMQ / 8);
        gate_kernel<<<NROWS / 256, 256, 0, stream>>>(w, cnt, rowlist, wgt);

        dim3 grid(DIMU / BN, NROWS / BM, NCH);
        moe_gemm_bf<<<grid, 256, 0, stream>>>(qb, Wb, cnt, rowlist, wgt, out);
    } else {
        int*   cnt     = (int*)ws;
        int*   rowlist = (int*)(ws + 256);
        float* wgt     = (float*)(ws + 256 + (size_t)NCH * NROWS * sizeof(int));

        hipMemsetAsync(cnt, 0, 256, stream);
        hipMemsetAsync(d_out, 0, (size_t)out_size * sizeof(float), stream);

        gate_kernel<<<NROWS / 256, 256, 0, stream>>>(w, cnt, rowlist, wgt);

        dim3 grid(DIMU / BN, NROWS / BM, NCH);
        moe_gemm_f32<<<grid, 256, 0, stream>>>(q, Ws, cnt, rowlist, wgt, out);
    }
}